// Round 29
// baseline (45.509 us; speedup 1.0000x reference)
//
#include <hip/hip_runtime.h>
#include <hip/hip_bf16.h>

#define DMODEL 1024
#define DH 64
#define BB 4
#define SS 2048
#define NROW (BB * SS)   // 8192
#define NS 16            // kv-splits per q-tile (4 blocks/CU co-resident)

typedef __attribute__((ext_vector_type(8))) short bf16x8;
typedef __attribute__((ext_vector_type(4))) float f32x4;

__device__ __forceinline__ unsigned short f2bf(float f) {
    __hip_bfloat16 h = __float2bfloat16(f);
    return __builtin_bit_cast(unsigned short, h);
}
__device__ __forceinline__ float bf2f(unsigned short u) {
    unsigned v = (unsigned)u << 16;
    return __builtin_bit_cast(float, v);
}

// ---------------- prep: Wt[192][1024] bf16 = [Wq|Wk|Wv]^T ----------------
__global__ __launch_bounds__(256) void prep_wt_kernel(
    const float* __restrict__ Wq, const float* __restrict__ Wk,
    const float* __restrict__ Wv, unsigned short* __restrict__ Wt)
{
    __shared__ float T[64][65];
    const int tid = threadIdx.x;
    const int m   = blockIdx.x;          // 0..2
    const int k0  = blockIdx.y * 64;     // k chunk
    const float* W = (m == 0) ? Wq : (m == 1) ? Wk : Wv;

    const int tn = tid & 63, tk = tid >> 6;
    #pragma unroll
    for (int j = 0; j < 16; ++j)
        T[4 * j + tk][tn] = W[(size_t)(k0 + 4 * j + tk) * DH + tn];
    __syncthreads();

    const int wk = tid & 63, wn = tid >> 6;
    #pragma unroll
    for (int j = 0; j < 16; ++j)
        Wt[(size_t)(m * 64 + 4 * j + wn) * DMODEL + k0 + wk] =
            f2bf(T[wk][4 * j + wn]);
}

// -------- QKV projection: 96-col B-panel, quarter-dbuf, counted vmcnt --------
// (round-22/23 structure — best measured proj)
__global__ __launch_bounds__(256) void qkv_proj_mfma(
    const float* __restrict__ emb, const unsigned short* __restrict__ Wt,
    const float* __restrict__ bq, const float* __restrict__ bk,
    const float* __restrict__ bv,
    unsigned short* __restrict__ Q, unsigned short* __restrict__ K,
    unsigned short* __restrict__ V)
{
    __shared__ unsigned short Bs[2][96][256];  // [buf][row][k-slot*8], 96 KB

    const int tid  = threadIdx.x;
    const int lane = tid & 63;
    const int w    = tid >> 6;          // 0..3
    const int c    = lane & 15;
    const int g    = lane >> 4;
    const int row0    = blockIdx.x * 64;
    const int colbase = blockIdx.y * 96;

    const float* arow = emb + (size_t)(row0 + 16 * w + c) * DMODEL + 8 * g;

    f32x4 acc[6];
    #pragma unroll
    for (int t = 0; t < 6; ++t) acc[t] = (f32x4){0.f, 0.f, 0.f, 0.f};

    float4 aR[4][4];

    const int lrow_off = lane >> 5;          // 0/1
    const int lslot    = lane & 31;

#define ISSUEB(QTR, BI) do {                                                  \
    _Pragma("unroll")                                                         \
    for (int j = 0; j < 12; ++j) {                                            \
        const int rb = 24 * w + 2 * j;                                        \
        const int rr = rb + lrow_off;                                         \
        __builtin_amdgcn_global_load_lds(                                     \
            (const __attribute__((address_space(1))) void*)(                  \
                Wt + (size_t)(colbase + rr) * DMODEL + (QTR) * 256            \
                   + 8 * (lslot ^ (rr & 7))),                                 \
            (__attribute__((address_space(3))) void*)&Bs[BI][rb][0],          \
            16, 0, 0);                                                        \
    }                                                                         \
} while (0)

#define LOADA(S, R) do {                                                      \
    aR[R][0] = *reinterpret_cast<const float4*>(arow + 64 * (S));             \
    aR[R][1] = *reinterpret_cast<const float4*>(arow + 64 * (S) + 4);         \
    aR[R][2] = *reinterpret_cast<const float4*>(arow + 64 * (S) + 32);        \
    aR[R][3] = *reinterpret_cast<const float4*>(arow + 64 * (S) + 36);        \
} while (0)

    ISSUEB(0, 0);
    LOADA(0, 0);
    LOADA(1, 1);
    LOADA(2, 2);
    asm volatile("s_waitcnt vmcnt(12)" ::: "memory");
    __builtin_amdgcn_sched_barrier(0);
    __syncthreads();                            // buf0 visible

    #pragma unroll
    for (int q = 0; q < 4; ++q) {
        const int bi = q & 1;
        if (q < 3) ISSUEB(q + 1, bi ^ 1);       // in flight during compute

        #pragma unroll
        for (int s2 = 0; s2 < 4; ++s2) {
            const int S = 4 * q + s2;
            const int r = S & 3;
            if (S + 3 < 16) LOADA(S + 3, (S + 3) & 3);

            bf16x8 af[2];
            {
                union { bf16x8 v; unsigned short u[8]; } p0, p1;
                p0.u[0] = f2bf(aR[r][0].x); p0.u[1] = f2bf(aR[r][0].y);
                p0.u[2] = f2bf(aR[r][0].z); p0.u[3] = f2bf(aR[r][0].w);
                p0.u[4] = f2bf(aR[r][1].x); p0.u[5] = f2bf(aR[r][1].y);
                p0.u[6] = f2bf(aR[r][1].z); p0.u[7] = f2bf(aR[r][1].w);
                p1.u[0] = f2bf(aR[r][2].x); p1.u[1] = f2bf(aR[r][2].y);
                p1.u[2] = f2bf(aR[r][2].z); p1.u[3] = f2bf(aR[r][2].w);
                p1.u[4] = f2bf(aR[r][3].x); p1.u[5] = f2bf(aR[r][3].y);
                p1.u[6] = f2bf(aR[r][3].z); p1.u[7] = f2bf(aR[r][3].w);
                af[0] = p0.v; af[1] = p1.v;
            }

            #pragma unroll
            for (int t = 0; t < 6; ++t)
                #pragma unroll
                for (int kp = 0; kp < 2; ++kp) {
                    const int row  = 16 * t + c;
                    const int slot = (8 * s2 + 4 * kp + g) ^ (row & 7);
                    bf16x8 bfr = __builtin_bit_cast(bf16x8,
                        *reinterpret_cast<const uint4*>(&Bs[bi][row][slot * 8]));
                    acc[t] = __builtin_amdgcn_mfma_f32_16x16x32_bf16(
                        af[kp], bfr, acc[t], 0, 0, 0);
                }
        }
        if (q < 3) {
            asm volatile("s_waitcnt vmcnt(12)" ::: "memory");
            __builtin_amdgcn_sched_barrier(0);
            __syncthreads();
        }
    }
#undef ISSUEB
#undef LOADA

    // epilogue: bias (+ 1/8 scale folded into Q), store bf16
    #pragma unroll
    for (int t = 0; t < 6; ++t) {
        const int col = colbase + 16 * t + c;
        const int m   = col >> 6;
        const int lc  = col & 63;
        const float* bias = (m == 0) ? bq : (m == 1) ? bk : bv;
        unsigned short* O = (m == 0) ? Q : (m == 1) ? K : V;
        const float bs    = bias[lc];
        const float scale = (m == 0) ? 0.125f : 1.0f;
        #pragma unroll
        for (int i = 0; i < 4; ++i) {
            const int rr = row0 + 16 * w + 4 * g + i;
            O[(size_t)rr * DH + lc] = f2bf((acc[t][i] + bs) * scale);
        }
    }
}

// ---------------- causal flash attention via MFMA, KV-split ----------------
// (round-23 structure: QBLK=128, 8 waves, bf16 partials; NS=16 for 4 blk/CU)
__global__ __launch_bounds__(512) void attn_mfma_split(
    const unsigned short* __restrict__ Q, const unsigned short* __restrict__ K,
    const unsigned short* __restrict__ V,
    unsigned short* __restrict__ Opart, float* __restrict__ mpart,
    float* __restrict__ lpart)
{
    __shared__ unsigned short Ks[64][72];      // [kv][d]
    __shared__ unsigned short Vt[64][72];      // [phys_d][kv], row-swizzled
    __shared__ unsigned short Ps[8][16][72];   // per-wave P rows [q-local][kv]

    const int tid  = threadIdx.x;
    const int lane = tid & 63;
    const int w    = tid >> 6;          // 0..7
    const int c    = lane & 15;
    const int g    = lane >> 4;
    const int qt   = blockIdx.x;        // 128-row q-tile, 0..15
    const int b    = blockIdx.y;
    const int sp   = blockIdx.z;
    const int q0   = qt * 128;

    const int ntile = 2 * qt + 2;       // 64-wide k-tiles needed
    const int kt0 = (ntile * sp) / NS;
    const int kt1 = (ntile * (sp + 1)) / NS;

    const unsigned short* Qb = Q + (size_t)b * SS * DH;
    const unsigned short* Kb = K + (size_t)b * SS * DH;
    const unsigned short* Vb = V + (size_t)b * SS * DH;

    bf16x8 qa[2];
    #pragma unroll
    for (int kp = 0; kp < 2; ++kp)
        qa[kp] = __builtin_bit_cast(bf16x8,
            *reinterpret_cast<const uint4*>(
                &Qb[(size_t)(q0 + 16 * w + c) * DH + 32 * kp + 8 * g]));

    f32x4 o[4];   // o[t][i] = O^T[d = 16t+4g+i][q = 16w+c], unnormalized
    #pragma unroll
    for (int t = 0; t < 4; ++t) o[t] = (f32x4){0.f, 0.f, 0.f, 0.f};
    float m_i = -1e30f;
    float l_i = 0.f;

    // staging: 512 threads, one K uint4 + one V uint4 each
    const int kvs = tid >> 3;           // 0..63
    const int m8  = tid & 7;
    const int d0  = m8 * 8;

    for (int kt = kt0; kt < kt1; ++kt) {
        const int kb0 = kt * 64;
        __syncthreads();
        {
            *reinterpret_cast<uint4*>(&Ks[kvs][d0]) =
                *reinterpret_cast<const uint4*>(&Kb[(size_t)(kb0 + kvs) * DH + d0]);
            const uint4 vv =
                *reinterpret_cast<const uint4*>(&Vb[(size_t)(kb0 + kvs) * DH + d0]);
            const unsigned wd[4] = {vv.x, vv.y, vv.z, vv.w};
            #pragma unroll
            for (int e = 0; e < 8; ++e)
                Vt[(d0 + e) ^ m8][kvs] =
                    (unsigned short)(wd[e >> 1] >> (16 * (e & 1)));
        }
        __syncthreads();

        f32x4 s[4];
        #pragma unroll
        for (int t = 0; t < 4; ++t) s[t] = (f32x4){0.f, 0.f, 0.f, 0.f};
        #pragma unroll
        for (int t = 0; t < 4; ++t)
            #pragma unroll
            for (int kp = 0; kp < 2; ++kp) {
                bf16x8 kf = __builtin_bit_cast(bf16x8,
                    *reinterpret_cast<const uint4*>(&Ks[16 * t + c][32 * kp + 8 * g]));
                s[t] = __builtin_amdgcn_mfma_f32_16x16x32_bf16(kf, qa[kp], s[t], 0, 0, 0);
            }

        // causal mask: diagonal region = last two k-tiles (kt >= 2*qt)
        if (kt >= 2 * qt) {
            const int qg = q0 + 16 * w + c;
            #pragma unroll
            for (int t = 0; t < 4; ++t)
                #pragma unroll
                for (int i = 0; i < 4; ++i)
                    if (kb0 + 16 * t + 4 * g + i > qg) s[t][i] = -1e30f;
        }

        float mx = m_i;
        #pragma unroll
        for (int t = 0; t < 4; ++t)
            mx = fmaxf(mx, fmaxf(fmaxf(s[t][0], s[t][1]), fmaxf(s[t][2], s[t][3])));
        mx = fmaxf(mx, __shfl_xor(mx, 16));
        mx = fmaxf(mx, __shfl_xor(mx, 32));
        const float al = __expf(m_i - mx);
        m_i = mx;
        float sum = 0.f;
        #pragma unroll
        for (int t = 0; t < 4; ++t)
            #pragma unroll
            for (int i = 0; i < 4; ++i) {
                const float p = __expf(s[t][i] - mx);
                s[t][i] = p;
                sum += p;
            }
        sum += __shfl_xor(sum, 16);
        sum += __shfl_xor(sum, 32);
        l_i = l_i * al + sum;

        #pragma unroll
        for (int t = 0; t < 4; ++t) {
            uint2 u;
            u.x = (unsigned)f2bf(s[t][0]) | ((unsigned)f2bf(s[t][1]) << 16);
            u.y = (unsigned)f2bf(s[t][2]) | ((unsigned)f2bf(s[t][3]) << 16);
            *reinterpret_cast<uint2*>(&Ps[w][c][16 * t + 4 * g]) = u;
        }

        #pragma unroll
        for (int t = 0; t < 4; ++t)
            #pragma unroll
            for (int i = 0; i < 4; ++i)
                o[t][i] *= al;

        #pragma unroll
        for (int kp = 0; kp < 2; ++kp) {
            bf16x8 pb = __builtin_bit_cast(bf16x8,
                *reinterpret_cast<const uint4*>(&Ps[w][c][32 * kp + 8 * g]));
            #pragma unroll
            for (int t = 0; t < 4; ++t) {
                const int dv = 16 * t + c;
                const int pr = dv ^ ((2 * t + (c >> 3)) & 7);
                bf16x8 vf = __builtin_bit_cast(bf16x8,
                    *reinterpret_cast<const uint4*>(&Vt[pr][32 * kp + 8 * g]));
                o[t] = __builtin_amdgcn_mfma_f32_16x16x32_bf16(vf, pb, o[t], 0, 0, 0);
            }
        }
    }

    // epilogue: bf16 unnormalized partials
    const int qrow = b * SS + q0 + 16 * w + c;
    #pragma unroll
    for (int t = 0; t < 4; ++t) {
        uint2 u;
        u.x = (unsigned)f2bf(o[t][0]) | ((unsigned)f2bf(o[t][1]) << 16);
        u.y = (unsigned)f2bf(o[t][2]) | ((unsigned)f2bf(o[t][3]) << 16);
        *reinterpret_cast<uint2*>(
            &Opart[((size_t)sp * NROW + qrow) * DH + 16 * t + 4 * g]) = u;
    }
    if (g == 0) {
        mpart[(size_t)sp * NROW + qrow] = m_i;
        lpart[(size_t)sp * NROW + qrow] = l_i;
    }
}

// ---------------- combine partials (bf16 Opart) ----------------
__global__ __launch_bounds__(256) void attn_combine(
    const unsigned short* __restrict__ Opart, const float* __restrict__ mpart,
    const float* __restrict__ lpart, float* __restrict__ out)
{
    const int idx = blockIdx.x * 256 + threadIdx.x;   // row*16 + d4
    const int row = idx >> 4;
    const int d4  = (idx & 15) * 4;

    float m[NS];
    float M = -1e30f;
    #pragma unroll
    for (int s = 0; s < NS; ++s) {
        m[s] = mpart[(size_t)s * NROW + row];
        M = fmaxf(M, m[s]);
    }
    float L = 0.f;
    float4 acc = {0.f, 0.f, 0.f, 0.f};
    #pragma unroll
    for (int s = 0; s < NS; ++s) {
        const float wgt = __expf(m[s] - M);
        L += wgt * lpart[(size_t)s * NROW + row];
        const uint2 pu = *reinterpret_cast<const uint2*>(
            &Opart[((size_t)s * NROW + row) * DH + d4]);
        acc.x += wgt * bf2f((unsigned short)(pu.x & 0xffff));
        acc.y += wgt * bf2f((unsigned short)(pu.x >> 16));
        acc.z += wgt * bf2f((unsigned short)(pu.y & 0xffff));
        acc.w += wgt * bf2f((unsigned short)(pu.y >> 16));
    }
    const float inv = 1.f / L;
    float4 r = {acc.x * inv, acc.y * inv, acc.z * inv, acc.w * inv};
    *reinterpret_cast<float4*>(&out[(size_t)row * DH + d4]) = r;
}

extern "C" void kernel_launch(void* const* d_in, const int* in_sizes, int n_in,
                              void* d_out, int out_size, void* d_ws, size_t ws_size,
                              hipStream_t stream) {
    const float* emb = (const float*)d_in[0];
    const float* Wq  = (const float*)d_in[1];
    const float* bq  = (const float*)d_in[2];
    const float* Wk  = (const float*)d_in[3];
    const float* bk  = (const float*)d_in[4];
    const float* Wv  = (const float*)d_in[5];
    const float* bv  = (const float*)d_in[6];
    float* out = (float*)d_out;

    unsigned short* Qw = (unsigned short*)d_ws;
    unsigned short* Kw = Qw + (size_t)NROW * DH;
    unsigned short* Vw = Kw + (size_t)NROW * DH;
    unsigned short* Wt = Vw + (size_t)NROW * DH;            // 192*1024 bf16
    unsigned short* Opart = Wt + (size_t)192 * DMODEL;      // [NS][NROW][DH] bf16
    float* mpart = (float*)(Opart + (size_t)NS * NROW * DH);
    float* lpart = mpart + (size_t)NS * NROW;

    hipLaunchKernelGGL(prep_wt_kernel, dim3(3, 16), dim3(256), 0, stream,
                       Wq, Wk, Wv, Wt);
    hipLaunchKernelGGL(qkv_proj_mfma, dim3(NROW / 64, 2), dim3(256), 0, stream,
                       emb, Wt, bq, bk, bv, Qw, Kw, Vw);
    hipLaunchKernelGGL(attn_mfma_split, dim3(SS / 128, BB, NS), dim3(512), 0, stream,
                       Qw, Kw, Vw, Opart, mpart, lpart);
    hipLaunchKernelGGL(attn_combine, dim3(NROW * 16 / 256), dim3(256), 0, stream,
                       Opart, mpart, lpart, out);
}

// Round 30
// 42.753 us; speedup vs baseline: 1.0644x; 1.0644x over previous
//
#include <hip/hip_runtime.h>
#include <hip/hip_bf16.h>

#define DMODEL 1024
#define DH 64
#define BB 4
#define SS 2048
#define NROW (BB * SS)   // 8192
#define NS 8             // kv-splits per q-tile (measured optimum)

typedef __attribute__((ext_vector_type(8))) short bf16x8;
typedef __attribute__((ext_vector_type(4))) float f32x4;

__device__ __forceinline__ unsigned short f2bf(float f) {
    __hip_bfloat16 h = __float2bfloat16(f);
    return __builtin_bit_cast(unsigned short, h);
}
__device__ __forceinline__ float bf2f(unsigned short u) {
    unsigned v = (unsigned)u << 16;
    return __builtin_bit_cast(float, v);
}

// ---------------- prep: Wt[192][1024] bf16 = [Wq|Wk|Wv]^T ----------------
__global__ __launch_bounds__(256) void prep_wt_kernel(
    const float* __restrict__ Wq, const float* __restrict__ Wk,
    const float* __restrict__ Wv, unsigned short* __restrict__ Wt)
{
    __shared__ float T[64][65];
    const int tid = threadIdx.x;
    const int m   = blockIdx.x;          // 0..2
    const int k0  = blockIdx.y * 64;     // k chunk
    const float* W = (m == 0) ? Wq : (m == 1) ? Wk : Wv;

    const int tn = tid & 63, tk = tid >> 6;
    #pragma unroll
    for (int j = 0; j < 16; ++j)
        T[4 * j + tk][tn] = W[(size_t)(k0 + 4 * j + tk) * DH + tn];
    __syncthreads();

    const int wk = tid & 63, wn = tid >> 6;
    #pragma unroll
    for (int j = 0; j < 16; ++j)
        Wt[(size_t)(m * 64 + 4 * j + wn) * DMODEL + k0 + wk] =
            f2bf(T[wk][4 * j + wn]);
}

// -------- QKV projection: 96-col B-panel, quarter-dbuf, counted vmcnt --------
// (round-22/23 structure — best measured proj)
__global__ __launch_bounds__(256) void qkv_proj_mfma(
    const float* __restrict__ emb, const unsigned short* __restrict__ Wt,
    const float* __restrict__ bq, const float* __restrict__ bk,
    const float* __restrict__ bv,
    unsigned short* __restrict__ Q, unsigned short* __restrict__ K,
    unsigned short* __restrict__ V)
{
    __shared__ unsigned short Bs[2][96][256];  // [buf][row][k-slot*8], 96 KB

    const int tid  = threadIdx.x;
    const int lane = tid & 63;
    const int w    = tid >> 6;          // 0..3
    const int c    = lane & 15;
    const int g    = lane >> 4;
    const int row0    = blockIdx.x * 64;
    const int colbase = blockIdx.y * 96;

    const float* arow = emb + (size_t)(row0 + 16 * w + c) * DMODEL + 8 * g;

    f32x4 acc[6];
    #pragma unroll
    for (int t = 0; t < 6; ++t) acc[t] = (f32x4){0.f, 0.f, 0.f, 0.f};

    float4 aR[4][4];

    const int lrow_off = lane >> 5;          // 0/1
    const int lslot    = lane & 31;

#define ISSUEB(QTR, BI) do {                                                  \
    _Pragma("unroll")                                                         \
    for (int j = 0; j < 12; ++j) {                                            \
        const int rb = 24 * w + 2 * j;                                        \
        const int rr = rb + lrow_off;                                         \
        __builtin_amdgcn_global_load_lds(                                     \
            (const __attribute__((address_space(1))) void*)(                  \
                Wt + (size_t)(colbase + rr) * DMODEL + (QTR) * 256            \
                   + 8 * (lslot ^ (rr & 7))),                                 \
            (__attribute__((address_space(3))) void*)&Bs[BI][rb][0],          \
            16, 0, 0);                                                        \
    }                                                                         \
} while (0)

#define LOADA(S, R) do {                                                      \
    aR[R][0] = *reinterpret_cast<const float4*>(arow + 64 * (S));             \
    aR[R][1] = *reinterpret_cast<const float4*>(arow + 64 * (S) + 4);         \
    aR[R][2] = *reinterpret_cast<const float4*>(arow + 64 * (S) + 32);        \
    aR[R][3] = *reinterpret_cast<const float4*>(arow + 64 * (S) + 36);        \
} while (0)

    ISSUEB(0, 0);
    LOADA(0, 0);
    LOADA(1, 1);
    LOADA(2, 2);
    asm volatile("s_waitcnt vmcnt(12)" ::: "memory");
    __builtin_amdgcn_sched_barrier(0);
    __syncthreads();                            // buf0 visible

    #pragma unroll
    for (int q = 0; q < 4; ++q) {
        const int bi = q & 1;
        if (q < 3) ISSUEB(q + 1, bi ^ 1);       // in flight during compute

        #pragma unroll
        for (int s2 = 0; s2 < 4; ++s2) {
            const int S = 4 * q + s2;
            const int r = S & 3;
            if (S + 3 < 16) LOADA(S + 3, (S + 3) & 3);

            bf16x8 af[2];
            {
                union { bf16x8 v; unsigned short u[8]; } p0, p1;
                p0.u[0] = f2bf(aR[r][0].x); p0.u[1] = f2bf(aR[r][0].y);
                p0.u[2] = f2bf(aR[r][0].z); p0.u[3] = f2bf(aR[r][0].w);
                p0.u[4] = f2bf(aR[r][1].x); p0.u[5] = f2bf(aR[r][1].y);
                p0.u[6] = f2bf(aR[r][1].z); p0.u[7] = f2bf(aR[r][1].w);
                p1.u[0] = f2bf(aR[r][2].x); p1.u[1] = f2bf(aR[r][2].y);
                p1.u[2] = f2bf(aR[r][2].z); p1.u[3] = f2bf(aR[r][2].w);
                p1.u[4] = f2bf(aR[r][3].x); p1.u[5] = f2bf(aR[r][3].y);
                p1.u[6] = f2bf(aR[r][3].z); p1.u[7] = f2bf(aR[r][3].w);
                af[0] = p0.v; af[1] = p1.v;
            }

            #pragma unroll
            for (int t = 0; t < 6; ++t)
                #pragma unroll
                for (int kp = 0; kp < 2; ++kp) {
                    const int row  = 16 * t + c;
                    const int slot = (8 * s2 + 4 * kp + g) ^ (row & 7);
                    bf16x8 bfr = __builtin_bit_cast(bf16x8,
                        *reinterpret_cast<const uint4*>(&Bs[bi][row][slot * 8]));
                    acc[t] = __builtin_amdgcn_mfma_f32_16x16x32_bf16(
                        af[kp], bfr, acc[t], 0, 0, 0);
                }
        }
        if (q < 3) {
            asm volatile("s_waitcnt vmcnt(12)" ::: "memory");
            __builtin_amdgcn_sched_barrier(0);
            __syncthreads();
        }
    }
#undef ISSUEB
#undef LOADA

    // epilogue: bias (+ 1/8 scale folded into Q), store bf16
    #pragma unroll
    for (int t = 0; t < 6; ++t) {
        const int col = colbase + 16 * t + c;
        const int m   = col >> 6;
        const int lc  = col & 63;
        const float* bias = (m == 0) ? bq : (m == 1) ? bk : bv;
        unsigned short* O = (m == 0) ? Q : (m == 1) ? K : V;
        const float bs    = bias[lc];
        const float scale = (m == 0) ? 0.125f : 1.0f;
        #pragma unroll
        for (int i = 0; i < 4; ++i) {
            const int rr = row0 + 16 * w + 4 * g + i;
            O[(size_t)rr * DH + lc] = f2bf((acc[t][i] + bs) * scale);
        }
    }
}

// ---------------- causal flash attention via MFMA, KV-split ----------------
// (round-23 structure, best measured: QBLK=128, 8 waves, bf16 partials, NS=8)
__global__ __launch_bounds__(512) void attn_mfma_split(
    const unsigned short* __restrict__ Q, const unsigned short* __restrict__ K,
    const unsigned short* __restrict__ V,
    unsigned short* __restrict__ Opart, float* __restrict__ mpart,
    float* __restrict__ lpart)
{
    __shared__ unsigned short Ks[64][72];      // [kv][d]
    __shared__ unsigned short Vt[64][72];      // [phys_d][kv], row-swizzled
    __shared__ unsigned short Ps[8][16][72];   // per-wave P rows [q-local][kv]

    const int tid  = threadIdx.x;
    const int lane = tid & 63;
    const int w    = tid >> 6;          // 0..7
    const int c    = lane & 15;
    const int g    = lane >> 4;
    const int qt   = blockIdx.x;        // 128-row q-tile, 0..15
    const int b    = blockIdx.y;
    const int sp   = blockIdx.z;
    const int q0   = qt * 128;

    const int ntile = 2 * qt + 2;       // 64-wide k-tiles needed
    const int kt0 = (ntile * sp) / NS;
    const int kt1 = (ntile * (sp + 1)) / NS;

    const unsigned short* Qb = Q + (size_t)b * SS * DH;
    const unsigned short* Kb = K + (size_t)b * SS * DH;
    const unsigned short* Vb = V + (size_t)b * SS * DH;

    bf16x8 qa[2];
    #pragma unroll
    for (int kp = 0; kp < 2; ++kp)
        qa[kp] = __builtin_bit_cast(bf16x8,
            *reinterpret_cast<const uint4*>(
                &Qb[(size_t)(q0 + 16 * w + c) * DH + 32 * kp + 8 * g]));

    f32x4 o[4];   // o[t][i] = O^T[d = 16t+4g+i][q = 16w+c], unnormalized
    #pragma unroll
    for (int t = 0; t < 4; ++t) o[t] = (f32x4){0.f, 0.f, 0.f, 0.f};
    float m_i = -1e30f;
    float l_i = 0.f;

    // staging: 512 threads, one K uint4 + one V uint4 each
    const int kvs = tid >> 3;           // 0..63
    const int m8  = tid & 7;
    const int d0  = m8 * 8;

    for (int kt = kt0; kt < kt1; ++kt) {
        const int kb0 = kt * 64;
        __syncthreads();
        {
            *reinterpret_cast<uint4*>(&Ks[kvs][d0]) =
                *reinterpret_cast<const uint4*>(&Kb[(size_t)(kb0 + kvs) * DH + d0]);
            const uint4 vv =
                *reinterpret_cast<const uint4*>(&Vb[(size_t)(kb0 + kvs) * DH + d0]);
            const unsigned wd[4] = {vv.x, vv.y, vv.z, vv.w};
            #pragma unroll
            for (int e = 0; e < 8; ++e)
                Vt[(d0 + e) ^ m8][kvs] =
                    (unsigned short)(wd[e >> 1] >> (16 * (e & 1)));
        }
        __syncthreads();

        f32x4 s[4];
        #pragma unroll
        for (int t = 0; t < 4; ++t) s[t] = (f32x4){0.f, 0.f, 0.f, 0.f};
        #pragma unroll
        for (int t = 0; t < 4; ++t)
            #pragma unroll
            for (int kp = 0; kp < 2; ++kp) {
                bf16x8 kf = __builtin_bit_cast(bf16x8,
                    *reinterpret_cast<const uint4*>(&Ks[16 * t + c][32 * kp + 8 * g]));
                s[t] = __builtin_amdgcn_mfma_f32_16x16x32_bf16(kf, qa[kp], s[t], 0, 0, 0);
            }

        // causal mask: diagonal region = last two k-tiles (kt >= 2*qt)
        if (kt >= 2 * qt) {
            const int qg = q0 + 16 * w + c;
            #pragma unroll
            for (int t = 0; t < 4; ++t)
                #pragma unroll
                for (int i = 0; i < 4; ++i)
                    if (kb0 + 16 * t + 4 * g + i > qg) s[t][i] = -1e30f;
        }

        float mx = m_i;
        #pragma unroll
        for (int t = 0; t < 4; ++t)
            mx = fmaxf(mx, fmaxf(fmaxf(s[t][0], s[t][1]), fmaxf(s[t][2], s[t][3])));
        mx = fmaxf(mx, __shfl_xor(mx, 16));
        mx = fmaxf(mx, __shfl_xor(mx, 32));
        const float al = __expf(m_i - mx);
        m_i = mx;
        float sum = 0.f;
        #pragma unroll
        for (int t = 0; t < 4; ++t)
            #pragma unroll
            for (int i = 0; i < 4; ++i) {
                const float p = __expf(s[t][i] - mx);
                s[t][i] = p;
                sum += p;
            }
        sum += __shfl_xor(sum, 16);
        sum += __shfl_xor(sum, 32);
        l_i = l_i * al + sum;

        #pragma unroll
        for (int t = 0; t < 4; ++t) {
            uint2 u;
            u.x = (unsigned)f2bf(s[t][0]) | ((unsigned)f2bf(s[t][1]) << 16);
            u.y = (unsigned)f2bf(s[t][2]) | ((unsigned)f2bf(s[t][3]) << 16);
            *reinterpret_cast<uint2*>(&Ps[w][c][16 * t + 4 * g]) = u;
        }

        #pragma unroll
        for (int t = 0; t < 4; ++t)
            #pragma unroll
            for (int i = 0; i < 4; ++i)
                o[t][i] *= al;

        #pragma unroll
        for (int kp = 0; kp < 2; ++kp) {
            bf16x8 pb = __builtin_bit_cast(bf16x8,
                *reinterpret_cast<const uint4*>(&Ps[w][c][32 * kp + 8 * g]));
            #pragma unroll
            for (int t = 0; t < 4; ++t) {
                const int dv = 16 * t + c;
                const int pr = dv ^ ((2 * t + (c >> 3)) & 7);
                bf16x8 vf = __builtin_bit_cast(bf16x8,
                    *reinterpret_cast<const uint4*>(&Vt[pr][32 * kp + 8 * g]));
                o[t] = __builtin_amdgcn_mfma_f32_16x16x32_bf16(vf, pb, o[t], 0, 0, 0);
            }
        }
    }

    // epilogue: bf16 unnormalized partials
    const int qrow = b * SS + q0 + 16 * w + c;
    #pragma unroll
    for (int t = 0; t < 4; ++t) {
        uint2 u;
        u.x = (unsigned)f2bf(o[t][0]) | ((unsigned)f2bf(o[t][1]) << 16);
        u.y = (unsigned)f2bf(o[t][2]) | ((unsigned)f2bf(o[t][3]) << 16);
        *reinterpret_cast<uint2*>(
            &Opart[((size_t)sp * NROW + qrow) * DH + 16 * t + 4 * g]) = u;
    }
    if (g == 0) {
        mpart[(size_t)sp * NROW + qrow] = m_i;
        lpart[(size_t)sp * NROW + qrow] = l_i;
    }
}

// ---------------- combine partials (bf16 Opart) ----------------
__global__ __launch_bounds__(256) void attn_combine(
    const unsigned short* __restrict__ Opart, const float* __restrict__ mpart,
    const float* __restrict__ lpart, float* __restrict__ out)
{
    const int idx = blockIdx.x * 256 + threadIdx.x;   // row*16 + d4
    const int row = idx >> 4;
    const int d4  = (idx & 15) * 4;

    float m[NS];
    float M = -1e30f;
    #pragma unroll
    for (int s = 0; s < NS; ++s) {
        m[s] = mpart[(size_t)s * NROW + row];
        M = fmaxf(M, m[s]);
    }
    float L = 0.f;
    float4 acc = {0.f, 0.f, 0.f, 0.f};
    #pragma unroll
    for (int s = 0; s < NS; ++s) {
        const float wgt = __expf(m[s] - M);
        L += wgt * lpart[(size_t)s * NROW + row];
        const uint2 pu = *reinterpret_cast<const uint2*>(
            &Opart[((size_t)s * NROW + row) * DH + d4]);
        acc.x += wgt * bf2f((unsigned short)(pu.x & 0xffff));
        acc.y += wgt * bf2f((unsigned short)(pu.x >> 16));
        acc.z += wgt * bf2f((unsigned short)(pu.y & 0xffff));
        acc.w += wgt * bf2f((unsigned short)(pu.y >> 16));
    }
    const float inv = 1.f / L;
    float4 r = {acc.x * inv, acc.y * inv, acc.z * inv, acc.w * inv};
    *reinterpret_cast<float4*>(&out[(size_t)row * DH + d4]) = r;
}

extern "C" void kernel_launch(void* const* d_in, const int* in_sizes, int n_in,
                              void* d_out, int out_size, void* d_ws, size_t ws_size,
                              hipStream_t stream) {
    const float* emb = (const float*)d_in[0];
    const float* Wq  = (const float*)d_in[1];
    const float* bq  = (const float*)d_in[2];
    const float* Wk  = (const float*)d_in[3];
    const float* bk  = (const float*)d_in[4];
    const float* Wv  = (const float*)d_in[5];
    const float* bv  = (const float*)d_in[6];
    float* out = (float*)d_out;

    unsigned short* Qw = (unsigned short*)d_ws;
    unsigned short* Kw = Qw + (size_t)NROW * DH;
    unsigned short* Vw = Kw + (size_t)NROW * DH;
    unsigned short* Wt = Vw + (size_t)NROW * DH;            // 192*1024 bf16
    unsigned short* Opart = Wt + (size_t)192 * DMODEL;      // [NS][NROW][DH] bf16
    float* mpart = (float*)(Opart + (size_t)NS * NROW * DH);
    float* lpart = mpart + (size_t)NS * NROW;

    hipLaunchKernelGGL(prep_wt_kernel, dim3(3, 16), dim3(256), 0, stream,
                       Wq, Wk, Wv, Wt);
    hipLaunchKernelGGL(qkv_proj_mfma, dim3(NROW / 64, 2), dim3(256), 0, stream,
                       emb, Wt, bq, bk, bv, Qw, Kw, Vw);
    hipLaunchKernelGGL(attn_mfma_split, dim3(SS / 128, BB, NS), dim3(512), 0, stream,
                       Qw, Kw, Vw, Opart, mpart, lpart);
    hipLaunchKernelGGL(attn_combine, dim3(NROW * 16 / 256), dim3(256), 0, stream,
                       Opart, mpart, lpart, out);
}